// Round 9
// baseline (211.967 us; speedup 1.0000x reference)
//
#include <hip/hip_runtime.h>
#include <math.h>

#define BB 64
#define TT 128
#define NN 64
#define HH 64
#define EE 128
#define KK 7
#define GG 192  // 3*H

typedef _Float16 half2_t __attribute__((ext_vector_type(2)));

__device__ __forceinline__ float sigmoidf_(float x){ return 1.f/(1.f+expf(-x)); }
__device__ __forceinline__ float fsig_(float x){
  return __builtin_amdgcn_rcpf(1.f + __builtin_amdgcn_exp2f(-1.44269504f * x));
}
__device__ __forceinline__ float ftanh_(float x){
  return fmaf(-2.f, __builtin_amdgcn_rcpf(1.f + __builtin_amdgcn_exp2f(2.88539008f * x)), 1.f);
}

#define PIPE_BARRIER() asm volatile("s_waitcnt lgkmcnt(0)\ns_barrier" ::: "memory")
#define LGKM0() asm volatile("s_waitcnt lgkmcnt(0)" ::: "memory")

__device__ __forceinline__ void loadrow_(float* d, const float* src){
  const float4* p = (const float4*)src;
  #pragma unroll
  for (int i = 0; i < 16; ++i) {
    float4 v = p[i];
    d[4*i] = v.x; d[4*i+1] = v.y; d[4*i+2] = v.z; d[4*i+3] = v.w;
  }
}
__device__ __forceinline__ void loadroww_(half2_t* d, const float* src){
  const float4* p = (const float4*)src;
  #pragma unroll
  for (int i = 0; i < 16; ++i) {
    float4 v = p[i];
    d[2*i]   = half2_t{(_Float16)v.x, (_Float16)v.y};
    d[2*i+1] = half2_t{(_Float16)v.z, (_Float16)v.w};
  }
}

// Conv1d (N->N, K=7, pad same) + SELU. 8 output channels per block.
__global__ void conv_selu_kernel(const float* __restrict__ x, const float* __restrict__ w,
                                 const float* __restrict__ bias,
                                 float* __restrict__ c_nt, float* __restrict__ c_btn) {
  const int og = blockIdx.x, b = blockIdx.y, t = threadIdx.x;
  const int o0 = og * 8;
  __shared__ __align__(16) float xs[NN][TT + 1];
  __shared__ __align__(16) float ws[NN * KK][8];
  for (int idx = t; idx < TT * NN; idx += 128) {
    int tt = idx >> 6, nn = idx & 63;
    xs[nn][tt] = x[(size_t)(b * TT + tt) * NN + nn];
  }
  for (int idx = t; idx < NN * KK * 8; idx += 128) {
    int oo = idx & 7, ik = idx >> 3;
    ws[ik][oo] = w[(size_t)(o0 + oo) * (NN * KK) + ik];
  }
  __syncthreads();
  float acc[8];
  #pragma unroll
  for (int oo = 0; oo < 8; ++oo) acc[oo] = bias[o0 + oo];
  for (int i = 0; i < NN; ++i) {
    #pragma unroll
    for (int k = 0; k < KK; ++k) {
      int tt = t + k - 3;
      if (tt >= 0 && tt < TT) {
        float xv = xs[i][tt];
        const float* wp = &ws[i * KK + k][0];
        float4 w0 = *(const float4*)wp;
        float4 w1 = *(const float4*)(wp + 4);
        acc[0] += xv * w0.x; acc[1] += xv * w0.y; acc[2] += xv * w0.z; acc[3] += xv * w0.w;
        acc[4] += xv * w1.x; acc[5] += xv * w1.y; acc[6] += xv * w1.z; acc[7] += xv * w1.w;
      }
    }
  }
  const float alpha = 1.6732632423543772f, scale = 1.0507009873554805f;
  #pragma unroll
  for (int oo = 0; oo < 8; ++oo) {
    float a = acc[oo];
    float r = a > 0.f ? scale * a : scale * alpha * expm1f(a);
    int o = o0 + oo;
    c_nt[((size_t)b * NN + o) * TT + t] = r;
    c_btn[((size_t)b * TT + t) * NN + o] = r;
  }
}

// Fused s1 + s2 projection
__global__ void s12_kernel(const float* __restrict__ c_nt, const float* __restrict__ Ww,
                           float* __restrict__ s1, float* __restrict__ s2) {
  const int m0 = blockIdx.x * 16, col = threadIdx.x;  // 128 threads
  __shared__ __align__(16) float ins[16][TT];
  for (int idx = col; idx < 16 * TT; idx += 128) {
    int r = idx >> 7, k = idx & 127;
    ins[r][k] = c_nt[(size_t)(m0 + r) * TT + k];
  }
  __syncthreads();
  const float* w1 = Ww + (size_t)col * (2 * TT);
  const float* w2 = w1 + TT;
  float acc1[16], acc2[16];
  #pragma unroll
  for (int r = 0; r < 16; ++r) { acc1[r] = 0.f; acc2[r] = 0.f; }
  #pragma unroll 2
  for (int k = 0; k < TT; k += 4) {
    float4 wv1 = *(const float4*)(w1 + k);
    float4 wv2 = *(const float4*)(w2 + k);
    #pragma unroll
    for (int r = 0; r < 16; ++r) {
      float4 iv = *(const float4*)&ins[r][k];
      acc1[r] += iv.x * wv1.x + iv.y * wv1.y + iv.z * wv1.z + iv.w * wv1.w;
      acc2[r] += iv.x * wv2.x + iv.y * wv2.y + iv.z * wv2.z + iv.w * wv2.w;
    }
  }
  #pragma unroll
  for (int r = 0; r < 16; ++r) {
    s1[(size_t)(m0 + r) * EE + col] = acc1[r];
    s2[(size_t)(m0 + r) * EE + col] = acc2[r];
  }
}

// GAT v2: 16 attention rows per block (staging amortized 16x). grid (4, B), 256 thr.
__global__ void gat_kernel(const float* __restrict__ s1, const float* __restrict__ s2,
                           const float* __restrict__ bw, const float* __restrict__ Wa,
                           const float* __restrict__ ba, const float* __restrict__ c_nt,
                           float* __restrict__ hmp) {
  const int it = blockIdx.x, b = blockIdx.y, tid = threadIdx.x;
  const int i0 = it * 16;
  __shared__ float s2s[NN][EE + 1];    // s2[b] + bw (stride 129: conflict-free scalar)
  __shared__ float s1b[16][EE];
  __shared__ float cs[NN][TT + 1];     // c_nt[b]
  __shared__ float was[EE];
  __shared__ float att[16][NN];
  for (int idx = tid; idx < NN * EE; idx += 256) {
    int j = idx >> 7, e = idx & 127;
    s2s[j][e] = s2[((size_t)b * NN + j) * EE + e] + bw[e];
  }
  for (int idx = tid; idx < 16 * EE; idx += 256) {
    int r = idx >> 7, e = idx & 127;
    s1b[r][e] = s1[((size_t)b * NN + i0 + r) * EE + e];
  }
  for (int idx = tid; idx < NN * TT; idx += 256) {
    int j = idx >> 7, t = idx & 127;
    cs[j][t] = c_nt[((size_t)b * NN + j) * TT + t];
  }
  if (tid < EE) was[tid] = Wa[tid];
  __syncthreads();
  const int wv = tid >> 6, j = tid & 63;
  #pragma unroll
  for (int pass = 0; pass < 4; ++pass) {
    const int il = pass * 4 + wv;
    float acc = 0.f;
    #pragma unroll 8
    for (int e = 0; e < EE; ++e) {
      float v = s1b[il][e] + s2s[j][e];
      v = v > 0.f ? v : 0.2f * v;
      acc += was[e] * v;
    }
    float ej = acc + ba[0];
    float mx = ej;
    for (int off = 32; off >= 1; off >>= 1) mx = fmaxf(mx, __shfl_xor(mx, off));
    float ex = __builtin_amdgcn_exp2f(1.44269504f * (ej - mx));
    float sm = ex;
    for (int off = 32; off >= 1; off >>= 1) sm += __shfl_xor(sm, off);
    att[il][j] = ex / sm;
  }
  __syncthreads();
  for (int o = tid; o < 16 * TT; o += 256) {
    int il = o >> 7, t = o & 127;
    float acc = 0.f;
    #pragma unroll 8
    for (int jj = 0; jj < NN; ++jj) acc += att[il][jj] * cs[jj][t];
    hmp[((size_t)b * TT + t) * NN + i0 + il] = sigmoidf_(acc);
  }
}

// Fused chain, 4 waves (one per SIMD), 2 matvecs/wave, in-register stage handoffs:
//  W0: stage c | q1 = We_ih@c(t)+be_ih (in-reg) | rec1 -> h1h[pw]
//  W1: stage hmp | q2 = Wm_ih[:, :64]@h1(t) + Wm_ih[:,64:]@hmp(t)+bm_ih -> q2[pw]
//  W2: rec2 (Wm_hh, q2[pr]) -> h2h[pw] | recon(t=p-4) from h3f[pr] | pred tail
//  W3: q3 = Wd_ih@h2(t) (in-reg) | rec3 -> h3h(self), h3f[pw], h0s@t0
__global__ __launch_bounds__(256, 1)
void fused_chain4(const float* __restrict__ c_btn, const float* __restrict__ hmp,
                  const float* __restrict__ We_ih, const float* __restrict__ be_ih,
                  const float* __restrict__ We_hh, const float* __restrict__ be_hh,
                  const float* __restrict__ Wm_ih, const float* __restrict__ bm_ih,
                  const float* __restrict__ Wm_hh, const float* __restrict__ bm_hh,
                  const float* __restrict__ Wd_ih, const float* __restrict__ bd_ih,
                  const float* __restrict__ Wd_hh, const float* __restrict__ bd_hh,
                  const float* __restrict__ W_dec, const float* __restrict__ b_dec,
                  const float* __restrict__ W_p1, const float* __restrict__ b_p1,
                  const float* __restrict__ W_p2, const float* __restrict__ b_p2,
                  float* __restrict__ recon, float* __restrict__ pred) {
  const int b = blockIdx.x, tid = threadIdx.x, wid = tid >> 6, g = tid & 63;
  __shared__ __align__(16) _Float16 cbuf[HH], mbuf[HH], h3h[HH];
  __shared__ __align__(16) _Float16 h1h[2][HH], h2h[2][HH];
  __shared__ __align__(16) float q2[2][GG], h3f[2][HH];
  __shared__ __align__(16) float h0s[HH], ps[HH];

  half2_t wxa[32], wxb[32], wxc[32];   // first matvec rows
  half2_t wya[32], wyb[32], wyc[32];   // second matvec rows
  float wdec[64];                      // W2: recon row fp32
  float b0 = 0.f, b1 = 0.f, b2 = 0.f, e0 = 0.f, e1 = 0.f, e2 = 0.f, bdc = 0.f;
  if (wid == 0) {
    loadroww_(wxa, We_ih + (size_t)g * HH);           // P1
    loadroww_(wxb, We_ih + (size_t)(g + 64) * HH);
    loadroww_(wxc, We_ih + (size_t)(g + 128) * HH);
    loadroww_(wya, We_hh + (size_t)g * HH);           // R1
    loadroww_(wyb, We_hh + (size_t)(g + 64) * HH);
    loadroww_(wyc, We_hh + (size_t)(g + 128) * HH);
    b0 = be_ih[g]; b1 = be_ih[64 + g]; b2 = be_ih[128 + g];
    e0 = be_hh[g]; e1 = be_hh[64 + g]; e2 = be_hh[128 + g];
  } else if (wid == 1) {
    loadroww_(wxa, Wm_ih + (size_t)g * 128);          // P2a (cols 0..63)
    loadroww_(wxb, Wm_ih + (size_t)(g + 64) * 128);
    loadroww_(wxc, Wm_ih + (size_t)(g + 128) * 128);
    loadroww_(wya, Wm_ih + (size_t)g * 128 + 64);     // P2b (cols 64..127)
    loadroww_(wyb, Wm_ih + (size_t)(g + 64) * 128 + 64);
    loadroww_(wyc, Wm_ih + (size_t)(g + 128) * 128 + 64);
    b0 = bm_ih[g]; b1 = bm_ih[64 + g]; b2 = bm_ih[128 + g];
  } else if (wid == 2) {
    loadroww_(wxa, Wm_hh + (size_t)g * HH);           // R2
    loadroww_(wxb, Wm_hh + (size_t)(g + 64) * HH);
    loadroww_(wxc, Wm_hh + (size_t)(g + 128) * HH);
    loadrow_(wdec, W_dec + (size_t)g * HH);           // recon
    b0 = bm_hh[g]; b1 = bm_hh[64 + g]; b2 = bm_hh[128 + g];
    bdc = b_dec[g];
  } else {
    loadroww_(wxa, Wd_ih + (size_t)g * HH);           // P3
    loadroww_(wxb, Wd_ih + (size_t)(g + 64) * HH);
    loadroww_(wxc, Wd_ih + (size_t)(g + 128) * HH);
    loadroww_(wya, Wd_hh + (size_t)g * HH);           // R3
    loadroww_(wyb, Wd_hh + (size_t)(g + 64) * HH);
    loadroww_(wyc, Wd_hh + (size_t)(g + 128) * HH);
    b0 = bd_ih[g]; b1 = bd_ih[64 + g]; b2 = bd_ih[128 + g];
    e0 = bd_hh[g]; e1 = bd_hh[64 + g]; e2 = bd_hh[128 + g];
  }
  if (wid == 0) {
    h1h[0][g] = (_Float16)0.f; h1h[1][g] = (_Float16)0.f;
    h2h[0][g] = (_Float16)0.f; h2h[1][g] = (_Float16)0.f;
    h3h[g]    = (_Float16)0.f;
  }
  // input prefetch (W0: c_btn, W1: hmp), depth 2
  const float* cb = c_btn + (size_t)b * TT * NN + g;
  const float* hm = hmp   + (size_t)b * TT * NN + g;
  float cc = 0.f, cn = 0.f;
  if (wid == 0) { cc = cb[0]; cn = cb[NN]; }
  if (wid == 1) { cc = hm[0]; cn = hm[NN]; }
  float hown = 0.f;
  __syncthreads();

  for (int p = 0; p < TT + 4; ++p) {
    const int pw = p & 1, pr = pw ^ 1;
    if (wid == 0) {
      int t = p;
      if (t < TT) {
        cbuf[g] = (_Float16)cc;
        float cl = 0.f;
        if (t + 2 < TT) cl = cb[(size_t)(t + 2) * NN];
        LGKM0();
        float a0 = b0, a1 = b1, a2 = b2, r0 = e0, r1 = e1, r2 = e2;
        const float4* c4 = (const float4*)&cbuf[0];
        const float4* h4 = (const float4*)&h1h[pr][0];
        #pragma unroll
        for (int ch = 0; ch < 8; ++ch) {
          float4 cv = c4[ch], hv = h4[ch];
          const half2_t* cq = (const half2_t*)&cv;
          const half2_t* hq = (const half2_t*)&hv;
          #pragma unroll
          for (int k = 0; k < 4; ++k) {
            int i = 4 * ch + k;
            a0 = __builtin_amdgcn_fdot2(cq[k], wxa[i], a0, false);
            a1 = __builtin_amdgcn_fdot2(cq[k], wxb[i], a1, false);
            a2 = __builtin_amdgcn_fdot2(cq[k], wxc[i], a2, false);
            r0 = __builtin_amdgcn_fdot2(hq[k], wya[i], r0, false);
            r1 = __builtin_amdgcn_fdot2(hq[k], wyb[i], r1, false);
            r2 = __builtin_amdgcn_fdot2(hq[k], wyc[i], r2, false);
          }
        }
        float r = fsig_(a0 + r0), z = fsig_(a1 + r1), n = ftanh_(a2 + r * r2);
        hown = fmaf(z, hown - n, n);
        h1h[pw][g] = (_Float16)hown;
        cc = cn; cn = cl;
      }
    } else if (wid == 1) {
      int t = p - 1;
      if (t >= 0 && t < TT) {
        mbuf[g] = (_Float16)cc;
        float cl = 0.f;
        if (t + 2 < TT) cl = hm[(size_t)(t + 2) * NN];
        LGKM0();
        float a0 = b0, a1 = b1, a2 = b2, r0 = 0.f, r1 = 0.f, r2 = 0.f;
        const float4* h4 = (const float4*)&h1h[pr][0];
        const float4* m4 = (const float4*)&mbuf[0];
        #pragma unroll
        for (int ch = 0; ch < 8; ++ch) {
          float4 hv = h4[ch], mv = m4[ch];
          const half2_t* hq = (const half2_t*)&hv;
          const half2_t* mq = (const half2_t*)&mv;
          #pragma unroll
          for (int k = 0; k < 4; ++k) {
            int i = 4 * ch + k;
            a0 = __builtin_amdgcn_fdot2(hq[k], wxa[i], a0, false);
            a1 = __builtin_amdgcn_fdot2(hq[k], wxb[i], a1, false);
            a2 = __builtin_amdgcn_fdot2(hq[k], wxc[i], a2, false);
            r0 = __builtin_amdgcn_fdot2(mq[k], wya[i], r0, false);
            r1 = __builtin_amdgcn_fdot2(mq[k], wyb[i], r1, false);
            r2 = __builtin_amdgcn_fdot2(mq[k], wyc[i], r2, false);
          }
        }
        q2[pw][g] = a0 + r0; q2[pw][64 + g] = a1 + r1; q2[pw][128 + g] = a2 + r2;
        cc = cn; cn = cl;
      }
    } else if (wid == 2) {
      int t = p - 2;
      if (t >= 0 && t < TT) {
        float a0 = b0, a1 = b1, a2 = b2;
        const float4* h4 = (const float4*)&h2h[pr][0];
        #pragma unroll
        for (int ch = 0; ch < 8; ++ch) {
          float4 hv = h4[ch];
          const half2_t* hq = (const half2_t*)&hv;
          #pragma unroll
          for (int k = 0; k < 4; ++k) {
            int i = 4 * ch + k;
            a0 = __builtin_amdgcn_fdot2(hq[k], wxa[i], a0, false);
            a1 = __builtin_amdgcn_fdot2(hq[k], wxb[i], a1, false);
            a2 = __builtin_amdgcn_fdot2(hq[k], wxc[i], a2, false);
          }
        }
        float r = fsig_(q2[pr][g] + a0), z = fsig_(q2[pr][64 + g] + a1);
        float n = ftanh_(q2[pr][128 + g] + r * a2);
        hown = fmaf(z, hown - n, n);
        h2h[pw][g] = (_Float16)hown;
      }
      int t4 = p - 4;
      if (t4 >= 0) {
        const float4* h4 = (const float4*)&h3f[pr][0];
        float a0 = bdc, a1 = 0.f;
        #pragma unroll
        for (int i = 0; i < 8; ++i) {
          float4 hv = h4[2 * i], hw = h4[2 * i + 1];
          a0 = fmaf(hv.x, wdec[8*i],   fmaf(hv.y, wdec[8*i+1], fmaf(hv.z, wdec[8*i+2], fmaf(hv.w, wdec[8*i+3], a0))));
          a1 = fmaf(hw.x, wdec[8*i+4], fmaf(hw.y, wdec[8*i+5], fmaf(hw.z, wdec[8*i+6], fmaf(hw.w, wdec[8*i+7], a1))));
        }
        recon[((size_t)b * TT + t4) * NN + g] = a0 + a1;
      }
    } else {
      int t = p - 3;
      if (t >= 0 && t < TT) {
        float a0 = b0, a1 = b1, a2 = b2, r0 = e0, r1 = e1, r2 = e2;
        const float4* h4 = (const float4*)&h2h[pr][0];
        const float4* o4 = (const float4*)&h3h[0];
        #pragma unroll
        for (int ch = 0; ch < 8; ++ch) {
          float4 hv = h4[ch], ov = o4[ch];
          const half2_t* hq = (const half2_t*)&hv;
          const half2_t* oq = (const half2_t*)&ov;
          #pragma unroll
          for (int k = 0; k < 4; ++k) {
            int i = 4 * ch + k;
            a0 = __builtin_amdgcn_fdot2(hq[k], wxa[i], a0, false);   // P3 (q3)
            a1 = __builtin_amdgcn_fdot2(hq[k], wxb[i], a1, false);
            a2 = __builtin_amdgcn_fdot2(hq[k], wxc[i], a2, false);
            r0 = __builtin_amdgcn_fdot2(oq[k], wya[i], r0, false);   // R3 matvec
            r1 = __builtin_amdgcn_fdot2(oq[k], wyb[i], r1, false);
            r2 = __builtin_amdgcn_fdot2(oq[k], wyc[i], r2, false);
          }
        }
        float r = fsig_(a0 + r0), z = fsig_(a1 + r1), n = ftanh_(a2 + r * r2);
        hown = fmaf(z, hown - n, n);
        h3h[g] = (_Float16)hown;     // after reads of old h3h this phase (in-wave order)
        h3f[pw][g] = hown;
        if (t == 0) h0s[g] = hown;
      }
    }
    PIPE_BARRIER();
  }

  // pred head on W2 (h0s final since phase 3; all barriers passed)
  if (wid == 2) {
    float w1r[64]; loadrow_(w1r, W_p1 + (size_t)g * HH);
    const float4* h4 = (const float4*)&h0s[0];
    float a = b_p1[g];
    #pragma unroll
    for (int i = 0; i < 16; ++i) {
      float4 hv = h4[i];
      a = fmaf(hv.x, w1r[4*i], fmaf(hv.y, w1r[4*i+1], fmaf(hv.z, w1r[4*i+2], fmaf(hv.w, w1r[4*i+3], a))));
    }
    ps[g] = fmaxf(a, 0.f);
    LGKM0();
    float w2r[64]; loadrow_(w2r, W_p2 + (size_t)g * HH);
    const float4* p4 = (const float4*)&ps[0];
    float c2 = b_p2[g];
    #pragma unroll
    for (int i = 0; i < 16; ++i) {
      float4 pv = p4[i];
      c2 = fmaf(pv.x, w2r[4*i], fmaf(pv.y, w2r[4*i+1], fmaf(pv.z, w2r[4*i+2], fmaf(pv.w, w2r[4*i+3], c2))));
    }
    pred[(size_t)b * NN + g] = c2;
  }
}

extern "C" void kernel_launch(void* const* d_in, const int* in_sizes, int n_in,
                              void* d_out, int out_size, void* d_ws, size_t ws_size,
                              hipStream_t stream) {
  const float* x      = (const float*)d_in[0];
  const float* conv_w = (const float*)d_in[2];
  const float* conv_b = (const float*)d_in[3];
  const float* We_ih  = (const float*)d_in[4];
  const float* We_hh  = (const float*)d_in[5];
  const float* be_ih  = (const float*)d_in[6];
  const float* be_hh  = (const float*)d_in[7];
  const float* Ww     = (const float*)d_in[8];
  const float* bw     = (const float*)d_in[9];
  const float* Wa     = (const float*)d_in[10];
  const float* ba     = (const float*)d_in[11];
  const float* Wm_ih  = (const float*)d_in[12];
  const float* Wm_hh  = (const float*)d_in[13];
  const float* bm_ih  = (const float*)d_in[14];
  const float* bm_hh  = (const float*)d_in[15];
  const float* Wd_ih  = (const float*)d_in[16];
  const float* Wd_hh  = (const float*)d_in[17];
  const float* bd_ih  = (const float*)d_in[18];
  const float* bd_hh  = (const float*)d_in[19];
  const float* W_dec  = (const float*)d_in[20];
  const float* b_dec  = (const float*)d_in[21];
  const float* W_p1   = (const float*)d_in[22];
  const float* b_p1   = (const float*)d_in[23];
  const float* W_p2   = (const float*)d_in[24];
  const float* b_p2   = (const float*)d_in[25];
  float* out = (float*)d_out;

  float* wsf   = (float*)d_ws;
  float* c_nt  = wsf;                 // B*N*T    = 524288
  float* c_btn = c_nt  + 524288;      // B*T*N    = 524288
  float* s1    = c_btn + 524288;      // B*N*E    = 524288
  float* s2    = s1    + 524288;      // B*N*E    = 524288
  float* hmp   = s2    + 524288;      // B*T*N    = 524288

  conv_selu_kernel<<<dim3(8, BB), 128, 0, stream>>>(x, conv_w, conv_b, c_nt, c_btn);
  s12_kernel<<<BB * NN / 16, 128, 0, stream>>>(c_nt, Ww, s1, s2);
  gat_kernel<<<dim3(4, BB), 256, 0, stream>>>(s1, s2, bw, Wa, ba, c_nt, hmp);
  fused_chain4<<<BB, 256, 0, stream>>>(c_btn, hmp,
                                       We_ih, be_ih, We_hh, be_hh,
                                       Wm_ih, bm_ih, Wm_hh, bm_hh,
                                       Wd_ih, bd_ih, Wd_hh, bd_hh,
                                       W_dec, b_dec, W_p1, b_p1, W_p2, b_p2,
                                       out, out + BB * TT * NN);
}

// Round 11
// 209.726 us; speedup vs baseline: 1.0107x; 1.0107x over previous
//
#include <hip/hip_runtime.h>
#include <math.h>

#define BB 64
#define TT 128
#define NN 64
#define HH 64
#define EE 128
#define KK 7
#define GG 192  // 3*H

typedef _Float16 half2_t __attribute__((ext_vector_type(2)));

__device__ __forceinline__ float sigmoidf_(float x){ return 1.f/(1.f+expf(-x)); }
__device__ __forceinline__ float fsig_(float x){
  return __builtin_amdgcn_rcpf(1.f + __builtin_amdgcn_exp2f(-1.44269504f * x));
}
__device__ __forceinline__ float ftanh_(float x){
  return fmaf(-2.f, __builtin_amdgcn_rcpf(1.f + __builtin_amdgcn_exp2f(2.88539008f * x)), 1.f);
}

#define PIPE_BARRIER() asm volatile("s_waitcnt lgkmcnt(0)\ns_barrier" ::: "memory")
#define LGKM0() asm volatile("s_waitcnt lgkmcnt(0)" ::: "memory")

__device__ __forceinline__ void loadrow_(float* d, const float* src){
  const float4* p = (const float4*)src;
  #pragma unroll
  for (int i = 0; i < 16; ++i) {
    float4 v = p[i];
    d[4*i] = v.x; d[4*i+1] = v.y; d[4*i+2] = v.z; d[4*i+3] = v.w;
  }
}
__device__ __forceinline__ void loadroww_(half2_t* d, const float* src){
  const float4* p = (const float4*)src;
  #pragma unroll
  for (int i = 0; i < 16; ++i) {
    float4 v = p[i];
    d[2*i]   = half2_t{(_Float16)v.x, (_Float16)v.y};
    d[2*i+1] = half2_t{(_Float16)v.z, (_Float16)v.w};
  }
}
// dual-operand 3+3 row matvec via v_dot2_f32_f16 (fp32 accumulate)
__device__ __forceinline__ void mv6_(const _Float16* xs, const _Float16* ys,
    const half2_t* wxa, const half2_t* wxb, const half2_t* wxc,
    const half2_t* wya, const half2_t* wyb, const half2_t* wyc,
    float& a0, float& a1, float& a2, float& r0, float& r1, float& r2){
  const float4* x4 = (const float4*)xs;
  const float4* y4 = (const float4*)ys;
  #pragma unroll
  for (int ch = 0; ch < 8; ++ch) {
    float4 xv = x4[ch], yv = y4[ch];
    const half2_t* xq = (const half2_t*)&xv;
    const half2_t* yq = (const half2_t*)&yv;
    #pragma unroll
    for (int k = 0; k < 4; ++k) {
      int i = 4 * ch + k;
      a0 = __builtin_amdgcn_fdot2(xq[k], wxa[i], a0, false);
      a1 = __builtin_amdgcn_fdot2(xq[k], wxb[i], a1, false);
      a2 = __builtin_amdgcn_fdot2(xq[k], wxc[i], a2, false);
      r0 = __builtin_amdgcn_fdot2(yq[k], wya[i], r0, false);
      r1 = __builtin_amdgcn_fdot2(yq[k], wyb[i], r1, false);
      r2 = __builtin_amdgcn_fdot2(yq[k], wyc[i], r2, false);
    }
  }
}
__device__ __forceinline__ void mv3_(const _Float16* xs,
    const half2_t* wxa, const half2_t* wxb, const half2_t* wxc,
    float& a0, float& a1, float& a2){
  const float4* x4 = (const float4*)xs;
  #pragma unroll
  for (int ch = 0; ch < 8; ++ch) {
    float4 xv = x4[ch];
    const half2_t* xq = (const half2_t*)&xv;
    #pragma unroll
    for (int k = 0; k < 4; ++k) {
      int i = 4 * ch + k;
      a0 = __builtin_amdgcn_fdot2(xq[k], wxa[i], a0, false);
      a1 = __builtin_amdgcn_fdot2(xq[k], wxb[i], a1, false);
      a2 = __builtin_amdgcn_fdot2(xq[k], wxc[i], a2, false);
    }
  }
}

// Conv1d (N->N, K=7, pad same) + SELU. 8 output channels per block.
__global__ void conv_selu_kernel(const float* __restrict__ x, const float* __restrict__ w,
                                 const float* __restrict__ bias,
                                 float* __restrict__ c_nt, float* __restrict__ c_btn) {
  const int og = blockIdx.x, b = blockIdx.y, t = threadIdx.x;
  const int o0 = og * 8;
  __shared__ __align__(16) float xs[NN][TT + 1];
  __shared__ __align__(16) float ws[NN * KK][8];
  for (int idx = t; idx < TT * NN; idx += 128) {
    int tt = idx >> 6, nn = idx & 63;
    xs[nn][tt] = x[(size_t)(b * TT + tt) * NN + nn];
  }
  for (int idx = t; idx < NN * KK * 8; idx += 128) {
    int oo = idx & 7, ik = idx >> 3;
    ws[ik][oo] = w[(size_t)(o0 + oo) * (NN * KK) + ik];
  }
  __syncthreads();
  float acc[8];
  #pragma unroll
  for (int oo = 0; oo < 8; ++oo) acc[oo] = bias[o0 + oo];
  for (int i = 0; i < NN; ++i) {
    #pragma unroll
    for (int k = 0; k < KK; ++k) {
      int tt = t + k - 3;
      if (tt >= 0 && tt < TT) {
        float xv = xs[i][tt];
        const float* wp = &ws[i * KK + k][0];
        float4 w0 = *(const float4*)wp;
        float4 w1 = *(const float4*)(wp + 4);
        acc[0] += xv * w0.x; acc[1] += xv * w0.y; acc[2] += xv * w0.z; acc[3] += xv * w0.w;
        acc[4] += xv * w1.x; acc[5] += xv * w1.y; acc[6] += xv * w1.z; acc[7] += xv * w1.w;
      }
    }
  }
  const float alpha = 1.6732632423543772f, scale = 1.0507009873554805f;
  #pragma unroll
  for (int oo = 0; oo < 8; ++oo) {
    float a = acc[oo];
    float r = a > 0.f ? scale * a : scale * alpha * expm1f(a);
    int o = o0 + oo;
    c_nt[((size_t)b * NN + o) * TT + t] = r;
    c_btn[((size_t)b * TT + t) * NN + o] = r;
  }
}

// Fused s1 + s2 projection
__global__ void s12_kernel(const float* __restrict__ c_nt, const float* __restrict__ Ww,
                           float* __restrict__ s1, float* __restrict__ s2) {
  const int m0 = blockIdx.x * 16, col = threadIdx.x;  // 128 threads
  __shared__ __align__(16) float ins[16][TT];
  for (int idx = col; idx < 16 * TT; idx += 128) {
    int r = idx >> 7, k = idx & 127;
    ins[r][k] = c_nt[(size_t)(m0 + r) * TT + k];
  }
  __syncthreads();
  const float* w1 = Ww + (size_t)col * (2 * TT);
  const float* w2 = w1 + TT;
  float acc1[16], acc2[16];
  #pragma unroll
  for (int r = 0; r < 16; ++r) { acc1[r] = 0.f; acc2[r] = 0.f; }
  #pragma unroll 2
  for (int k = 0; k < TT; k += 4) {
    float4 wv1 = *(const float4*)(w1 + k);
    float4 wv2 = *(const float4*)(w2 + k);
    #pragma unroll
    for (int r = 0; r < 16; ++r) {
      float4 iv = *(const float4*)&ins[r][k];
      acc1[r] += iv.x * wv1.x + iv.y * wv1.y + iv.z * wv1.z + iv.w * wv1.w;
      acc2[r] += iv.x * wv2.x + iv.y * wv2.y + iv.z * wv2.z + iv.w * wv2.w;
    }
  }
  #pragma unroll
  for (int r = 0; r < 16; ++r) {
    s1[(size_t)(m0 + r) * EE + col] = acc1[r];
    s2[(size_t)(m0 + r) * EE + col] = acc2[r];
  }
}

// GAT v2: 16 attention rows per block. grid (4, B), 256 thr.
__global__ void gat_kernel(const float* __restrict__ s1, const float* __restrict__ s2,
                           const float* __restrict__ bw, const float* __restrict__ Wa,
                           const float* __restrict__ ba, const float* __restrict__ c_nt,
                           float* __restrict__ hmp) {
  const int it = blockIdx.x, b = blockIdx.y, tid = threadIdx.x;
  const int i0 = it * 16;
  __shared__ float s2s[NN][EE + 1];
  __shared__ float s1b[16][EE];
  __shared__ float cs[NN][TT + 1];
  __shared__ float was[EE];
  __shared__ float att[16][NN];
  for (int idx = tid; idx < NN * EE; idx += 256) {
    int j = idx >> 7, e = idx & 127;
    s2s[j][e] = s2[((size_t)b * NN + j) * EE + e] + bw[e];
  }
  for (int idx = tid; idx < 16 * EE; idx += 256) {
    int r = idx >> 7, e = idx & 127;
    s1b[r][e] = s1[((size_t)b * NN + i0 + r) * EE + e];
  }
  for (int idx = tid; idx < NN * TT; idx += 256) {
    int j = idx >> 7, t = idx & 127;
    cs[j][t] = c_nt[((size_t)b * NN + j) * TT + t];
  }
  if (tid < EE) was[tid] = Wa[tid];
  __syncthreads();
  const int wv = tid >> 6, j = tid & 63;
  #pragma unroll
  for (int pass = 0; pass < 4; ++pass) {
    const int il = pass * 4 + wv;
    float acc = 0.f;
    #pragma unroll 8
    for (int e = 0; e < EE; ++e) {
      float v = s1b[il][e] + s2s[j][e];
      v = v > 0.f ? v : 0.2f * v;
      acc += was[e] * v;
    }
    float ej = acc + ba[0];
    float mx = ej;
    for (int off = 32; off >= 1; off >>= 1) mx = fmaxf(mx, __shfl_xor(mx, off));
    float ex = __builtin_amdgcn_exp2f(1.44269504f * (ej - mx));
    float sm = ex;
    for (int off = 32; off >= 1; off >>= 1) sm += __shfl_xor(sm, off);
    att[il][j] = ex / sm;
  }
  __syncthreads();
  for (int o = tid; o < 16 * TT; o += 256) {
    int il = o >> 7, t = o & 127;
    float acc = 0.f;
    #pragma unroll 8
    for (int jj = 0; jj < NN; ++jj) acc += att[il][jj] * cs[jj][t];
    hmp[((size_t)b * TT + t) * NN + i0 + il] = sigmoidf_(acc);
  }
}

// Fused chain, 4 waves, K4=4 timesteps per barrier phase (36 phases).
#define K4 4
__global__ __launch_bounds__(256, 1)
void fused_chain4k(const float* __restrict__ c_btn, const float* __restrict__ hmp,
                   const float* __restrict__ We_ih, const float* __restrict__ be_ih,
                   const float* __restrict__ We_hh, const float* __restrict__ be_hh,
                   const float* __restrict__ Wm_ih, const float* __restrict__ bm_ih,
                   const float* __restrict__ Wm_hh, const float* __restrict__ bm_hh,
                   const float* __restrict__ Wd_ih, const float* __restrict__ bd_ih,
                   const float* __restrict__ Wd_hh, const float* __restrict__ bd_hh,
                   const float* __restrict__ W_dec, const float* __restrict__ b_dec,
                   const float* __restrict__ W_p1, const float* __restrict__ b_p1,
                   const float* __restrict__ W_p2, const float* __restrict__ b_p2,
                   float* __restrict__ recon, float* __restrict__ pred) {
  const int b = blockIdx.x, tid = threadIdx.x, wid = tid >> 6, g = tid & 63;
  __shared__ __align__(16) _Float16 cbuf[2][K4][HH], mbuf[2][K4][HH];
  __shared__ __align__(16) _Float16 h1h[2][K4][HH], h2h[2][K4][HH], h3h[2][K4][HH];
  __shared__ __align__(16) float q2[2][K4][GG], h3f[2][K4][HH];
  __shared__ __align__(16) float h0s[HH], ps[HH];

  // ---- zero ALL handoff LDS (leftover garbage can be f16-NaN; R9 bug:
  // only pr=1 slots were init'd but wave3's first read is h3h[0][K4-1]) ----
  {
    _Float16* z1 = &h1h[0][0][0];
    _Float16* z2 = &h2h[0][0][0];
    _Float16* z3 = &h3h[0][0][0];
    _Float16* z4 = &cbuf[0][0][0];
    _Float16* z5 = &mbuf[0][0][0];
    for (int idx = tid; idx < 2 * K4 * HH; idx += 256) {
      z1[idx] = (_Float16)0.f; z2[idx] = (_Float16)0.f; z3[idx] = (_Float16)0.f;
      z4[idx] = (_Float16)0.f; z5[idx] = (_Float16)0.f;
    }
    float* zf = &h3f[0][0][0];
    for (int idx = tid; idx < 2 * K4 * HH; idx += 256) zf[idx] = 0.f;
    float* zq = &q2[0][0][0];
    for (int idx = tid; idx < 2 * K4 * GG; idx += 256) zq[idx] = 0.f;
  }

  half2_t wxa[32], wxb[32], wxc[32];
  half2_t wya[32], wyb[32], wyc[32];
  float wdec[64];
  float b0 = 0.f, b1 = 0.f, b2 = 0.f, e0 = 0.f, e1 = 0.f, e2 = 0.f, bdc = 0.f;
  if (wid == 0) {
    loadroww_(wxa, We_ih + (size_t)g * HH);
    loadroww_(wxb, We_ih + (size_t)(g + 64) * HH);
    loadroww_(wxc, We_ih + (size_t)(g + 128) * HH);
    loadroww_(wya, We_hh + (size_t)g * HH);
    loadroww_(wyb, We_hh + (size_t)(g + 64) * HH);
    loadroww_(wyc, We_hh + (size_t)(g + 128) * HH);
    b0 = be_ih[g]; b1 = be_ih[64 + g]; b2 = be_ih[128 + g];
    e0 = be_hh[g]; e1 = be_hh[64 + g]; e2 = be_hh[128 + g];
  } else if (wid == 1) {
    loadroww_(wxa, Wm_ih + (size_t)g * 128);
    loadroww_(wxb, Wm_ih + (size_t)(g + 64) * 128);
    loadroww_(wxc, Wm_ih + (size_t)(g + 128) * 128);
    loadroww_(wya, Wm_ih + (size_t)g * 128 + 64);
    loadroww_(wyb, Wm_ih + (size_t)(g + 64) * 128 + 64);
    loadroww_(wyc, Wm_ih + (size_t)(g + 128) * 128 + 64);
    b0 = bm_ih[g]; b1 = bm_ih[64 + g]; b2 = bm_ih[128 + g];
  } else if (wid == 2) {
    loadroww_(wxa, Wm_hh + (size_t)g * HH);
    loadroww_(wxb, Wm_hh + (size_t)(g + 64) * HH);
    loadroww_(wxc, Wm_hh + (size_t)(g + 128) * HH);
    loadrow_(wdec, W_dec + (size_t)g * HH);
    b0 = bm_hh[g]; b1 = bm_hh[64 + g]; b2 = bm_hh[128 + g];
    bdc = b_dec[g];
  } else {
    loadroww_(wxa, Wd_ih + (size_t)g * HH);
    loadroww_(wxb, Wd_ih + (size_t)(g + 64) * HH);
    loadroww_(wxc, Wd_ih + (size_t)(g + 128) * HH);
    loadroww_(wya, Wd_hh + (size_t)g * HH);
    loadroww_(wyb, Wd_hh + (size_t)(g + 64) * HH);
    loadroww_(wyc, Wd_hh + (size_t)(g + 128) * HH);
    b0 = bd_ih[g]; b1 = bd_ih[64 + g]; b2 = bd_ih[128 + g];
    e0 = bd_hh[g]; e1 = bd_hh[64 + g]; e2 = bd_hh[128 + g];
  }
  const float* cb = c_btn + (size_t)b * TT * NN + g;
  const float* hm = hmp   + (size_t)b * TT * NN + g;
  float cur[K4], nxt[K4];
  #pragma unroll
  for (int s = 0; s < K4; ++s) { cur[s] = 0.f; nxt[s] = 0.f; }
  if (wid == 0) {
    #pragma unroll
    for (int s = 0; s < K4; ++s) cur[s] = cb[(size_t)s * NN];
  }
  if (wid == 1) {
    #pragma unroll
    for (int s = 0; s < K4; ++s) cur[s] = hm[(size_t)s * NN];
  }
  float hown = 0.f;
  __syncthreads();

  const int NPH = TT / K4 + 4;   // 36
  for (int p = 0; p < NPH; ++p) {
    const int pw = p & 1, pr = pw ^ 1;
    if (wid == 0) {
      if (p <= TT / K4 - 1) {
        const int t0 = p * K4;
        #pragma unroll
        for (int s = 0; s < K4; ++s) cbuf[pw][s][g] = (_Float16)cur[s];
        #pragma unroll
        for (int s = 0; s < K4; ++s)
          nxt[s] = (t0 + K4 + s < TT) ? cb[(size_t)(t0 + K4 + s) * NN] : 0.f;
        #pragma unroll
        for (int s = 0; s < K4; ++s) {
          const _Float16* hp = (s == 0) ? &h1h[pr][K4-1][0] : &h1h[pw][s-1][0];
          LGKM0();   // flush previous h write before reading
          float a0 = b0, a1 = b1, a2 = b2, r0 = e0, r1 = e1, r2 = e2;
          mv6_(&cbuf[pw][s][0], hp, wxa, wxb, wxc, wya, wyb, wyc, a0, a1, a2, r0, r1, r2);
          float r = fsig_(a0 + r0), z = fsig_(a1 + r1), n = ftanh_(a2 + r * r2);
          hown = fmaf(z, hown - n, n);
          h1h[pw][s][g] = (_Float16)hown;
        }
        #pragma unroll
        for (int s = 0; s < K4; ++s) cur[s] = nxt[s];
      }
    } else if (wid == 1) {
      if (p >= 1 && p <= TT / K4) {
        const int t0 = p * K4;   // next-phase base for prefetch
        #pragma unroll
        for (int s = 0; s < K4; ++s) mbuf[pw][s][g] = (_Float16)cur[s];
        #pragma unroll
        for (int s = 0; s < K4; ++s)
          nxt[s] = (t0 + s < TT) ? hm[(size_t)(t0 + s) * NN] : 0.f;
        LGKM0();
        #pragma unroll
        for (int s = 0; s < K4; ++s) {
          float a0 = b0, a1 = b1, a2 = b2, r0 = 0.f, r1 = 0.f, r2 = 0.f;
          mv6_(&h1h[pr][s][0], &mbuf[pw][s][0], wxa, wxb, wxc, wya, wyb, wyc,
               a0, a1, a2, r0, r1, r2);
          q2[pw][s][g] = a0 + r0; q2[pw][s][64 + g] = a1 + r1; q2[pw][s][128 + g] = a2 + r2;
        }
        #pragma unroll
        for (int s = 0; s < K4; ++s) cur[s] = nxt[s];
      }
    } else if (wid == 2) {
      if (p >= 2 && p <= TT / K4 + 1) {
        #pragma unroll
        for (int s = 0; s < K4; ++s) {
          const _Float16* hp = (s == 0) ? &h2h[pr][K4-1][0] : &h2h[pw][s-1][0];
          LGKM0();
          float a0 = b0, a1 = b1, a2 = b2;
          mv3_(hp, wxa, wxb, wxc, a0, a1, a2);
          float r = fsig_(q2[pr][s][g] + a0), z = fsig_(q2[pr][s][64 + g] + a1);
          float n = ftanh_(q2[pr][s][128 + g] + r * a2);
          hown = fmaf(z, hown - n, n);
          h2h[pw][s][g] = (_Float16)hown;
        }
      }
      if (p >= 4) {
        #pragma unroll
        for (int s = 0; s < K4; ++s) {
          int t4 = (p - 4) * K4 + s;
          const float4* h4 = (const float4*)&h3f[pr][s][0];
          float a0 = bdc, a1 = 0.f;
          #pragma unroll
          for (int i = 0; i < 8; ++i) {
            float4 hv = h4[2 * i], hw = h4[2 * i + 1];
            a0 = fmaf(hv.x, wdec[8*i],   fmaf(hv.y, wdec[8*i+1], fmaf(hv.z, wdec[8*i+2], fmaf(hv.w, wdec[8*i+3], a0))));
            a1 = fmaf(hw.x, wdec[8*i+4], fmaf(hw.y, wdec[8*i+5], fmaf(hw.z, wdec[8*i+6], fmaf(hw.w, wdec[8*i+7], a1))));
          }
          recon[((size_t)b * TT + t4) * NN + g] = a0 + a1;
        }
      }
    } else {
      if (p >= 3 && p <= TT / K4 + 2) {
        const int t0 = (p - 3) * K4;
        #pragma unroll
        for (int s = 0; s < K4; ++s) {
          const _Float16* op = (s == 0) ? &h3h[pr][K4-1][0] : &h3h[pw][s-1][0];
          LGKM0();
          float a0 = b0, a1 = b1, a2 = b2, r0 = e0, r1 = e1, r2 = e2;
          mv6_(&h2h[pr][s][0], op, wxa, wxb, wxc, wya, wyb, wyc, a0, a1, a2, r0, r1, r2);
          float r = fsig_(a0 + r0), z = fsig_(a1 + r1), n = ftanh_(a2 + r * r2);
          hown = fmaf(z, hown - n, n);
          h3h[pw][s][g] = (_Float16)hown;
          h3f[pw][s][g] = hown;
          if (t0 + s == 0) h0s[g] = hown;
        }
      }
    }
    PIPE_BARRIER();
  }

  // pred head on W2
  if (wid == 2) {
    float w1r[64]; loadrow_(w1r, W_p1 + (size_t)g * HH);
    const float4* h4 = (const float4*)&h0s[0];
    float a = b_p1[g];
    #pragma unroll
    for (int i = 0; i < 16; ++i) {
      float4 hv = h4[i];
      a = fmaf(hv.x, w1r[4*i], fmaf(hv.y, w1r[4*i+1], fmaf(hv.z, w1r[4*i+2], fmaf(hv.w, w1r[4*i+3], a))));
    }
    ps[g] = fmaxf(a, 0.f);
    LGKM0();
    float w2r[64]; loadrow_(w2r, W_p2 + (size_t)g * HH);
    const float4* p4 = (const float4*)&ps[0];
    float c2 = b_p2[g];
    #pragma unroll
    for (int i = 0; i < 16; ++i) {
      float4 pv = p4[i];
      c2 = fmaf(pv.x, w2r[4*i], fmaf(pv.y, w2r[4*i+1], fmaf(pv.z, w2r[4*i+2], fmaf(pv.w, w2r[4*i+3], c2))));
    }
    pred[(size_t)b * NN + g] = c2;
  }
}

extern "C" void kernel_launch(void* const* d_in, const int* in_sizes, int n_in,
                              void* d_out, int out_size, void* d_ws, size_t ws_size,
                              hipStream_t stream) {
  const float* x      = (const float*)d_in[0];
  const float* conv_w = (const float*)d_in[2];
  const float* conv_b = (const float*)d_in[3];
  const float* We_ih  = (const float*)d_in[4];
  const float* We_hh  = (const float*)d_in[5];
  const float* be_ih  = (const float*)d_in[6];
  const float* be_hh  = (const float*)d_in[7];
  const float* Ww     = (const float*)d_in[8];
  const float* bw     = (const float*)d_in[9];
  const float* Wa     = (const float*)d_in[10];
  const float* ba     = (const float*)d_in[11];
  const float* Wm_ih  = (const float*)d_in[12];
  const float* Wm_hh  = (const float*)d_in[13];
  const float* bm_ih  = (const float*)d_in[14];
  const float* bm_hh  = (const float*)d_in[15];
  const float* Wd_ih  = (const float*)d_in[16];
  const float* Wd_hh  = (const float*)d_in[17];
  const float* bd_ih  = (const float*)d_in[18];
  const float* bd_hh  = (const float*)d_in[19];
  const float* W_dec  = (const float*)d_in[20];
  const float* b_dec  = (const float*)d_in[21];
  const float* W_p1   = (const float*)d_in[22];
  const float* b_p1   = (const float*)d_in[23];
  const float* W_p2   = (const float*)d_in[24];
  const float* b_p2   = (const float*)d_in[25];
  float* out = (float*)d_out;

  float* wsf   = (float*)d_ws;
  float* c_nt  = wsf;                 // B*N*T    = 524288
  float* c_btn = c_nt  + 524288;      // B*T*N    = 524288
  float* s1    = c_btn + 524288;      // B*N*E    = 524288
  float* s2    = s1    + 524288;      // B*N*E    = 524288
  float* hmp   = s2    + 524288;      // B*T*N    = 524288

  conv_selu_kernel<<<dim3(8, BB), 128, 0, stream>>>(x, conv_w, conv_b, c_nt, c_btn);
  s12_kernel<<<BB * NN / 16, 128, 0, stream>>>(c_nt, Ww, s1, s2);
  gat_kernel<<<dim3(4, BB), 256, 0, stream>>>(s1, s2, bw, Wa, ba, c_nt, hmp);
  fused_chain4k<<<BB, 256, 0, stream>>>(c_btn, hmp,
                                        We_ih, be_ih, We_hh, be_hh,
                                        Wm_ih, bm_ih, Wm_hh, bm_hh,
                                        Wd_ih, bd_ih, Wd_hh, bd_hh,
                                        W_dec, b_dec, W_p1, b_p1, W_p2, b_p2,
                                        out, out + BB * TT * NN);
}